// Round 9
// baseline (194.205 us; speedup 1.0000x reference)
//
#include <hip/hip_runtime.h>
#include <math.h>

#define N_ROWS 131072
#define DIMS 64
#define K_CODES 512
#define XS_STRIDE 68
#define NBLK 2048

typedef __attribute__((ext_vector_type(8))) short bf16x8;
typedef __attribute__((ext_vector_type(4))) float f32x4;

union B8 { uint4 u; bf16x8 h; };

// RNE float->bf16 pack (two floats -> one uint, low=first)
__device__ inline unsigned bpack(float a, float b) {
  unsigned ua = __float_as_uint(a), ub = __float_as_uint(b);
  ua = (ua + 0x7FFFu + ((ua >> 16) & 1u)) >> 16;
  ub = (ub + 0x7FFFu + ((ub >> 16) & 1u)) >> 16;
  return ua | (ub << 16);
}

// exact reference dot: single fmaf chain over ascending d (bitwise as prior rounds)
__device__ inline float exact_dot(const float* __restrict__ xr, const float* __restrict__ cr) {
  float m = 0.f;
  #pragma unroll
  for (int d4 = 0; d4 < 16; ++d4) {
    const float4 c = *(const float4*)&cr[d4 * 4];
    const float4 x = *(const float4*)&xr[d4 * 4];
    m = fmaf(x.x, c.x, m);
    m = fmaf(x.y, c.y, m);
    m = fmaf(x.z, c.z, m);
    m = fmaf(x.w, c.w, m);
  }
  return m;
}

// ---------------- K0 (64 blocks, fully parallel): bins zero + exact c2 + bf16 frags
// cbB layout (as passing rounds): entry e = ct*128 + lane*2 + half;
//   code = ct*16 + (lane&15), dims [(lane>>4)*8 + half*32 .. +8). Plain bf16(c).
__global__ __launch_bounds__(256) void vq_init(const float* __restrict__ codebook,
                                               int* __restrict__ bins,
                                               float* __restrict__ c2g,
                                               uint4* __restrict__ cbB,
                                               int* __restrict__ done_cnt) {
  #pragma clang fp contract(off)
  const int t = threadIdx.x;
  const int b = blockIdx.x;
  if (t < 64) {
    const int e = b * 64 + t;          // 64 blocks x 64 = 4096 entries
    const int ct = e >> 7;
    const int q = e & 127;
    const int lane_id = q >> 1;
    const int half = q & 1;
    const int code = ct * 16 + (lane_id & 15);
    const int dbase = ((lane_id >> 4) * 8) + half * 32;
    const float* src = codebook + code * DIMS + dbase;
    const float4 a = *(const float4*)&src[0];
    const float4 c = *(const float4*)&src[4];
    uint4 u;
    u.x = bpack(a.x, a.y);
    u.y = bpack(a.z, a.w);
    u.z = bpack(c.x, c.y);
    u.w = bpack(c.z, c.w);
    cbB[e] = u;
  } else if (t < 72) {
    // exact c2: numpy pairwise_sum, n=64 (bitwise as prior passing rounds)
    const int k = b * 8 + (t - 64);
    const float* cr = codebook + k * DIMS;
    float r[8];
    #pragma unroll
    for (int j = 0; j < 8; ++j) r[j] = cr[j] * cr[j];
    for (int i = 8; i < 64; i += 8) {
      #pragma unroll
      for (int j = 0; j < 8; ++j) r[j] += cr[i + j] * cr[i + j];  // contract OFF
    }
    c2g[k] = ((r[0] + r[1]) + (r[2] + r[3])) + ((r[4] + r[5]) + (r[6] + r[7]));
  } else if (t < 80) {
    bins[b * 8 + (t - 72)] = 0;
  } else if (t == 80 && b == 0) {
    *done_cnt = 0;
  }
}

// ---------------- K1: MFMA approx scores -> candidates -> exact rescore -> outputs
// Round-7 proven core (78 us measured): wave w covers all 64 rows (4 M-tiles) x its
// code quarter (8 tiles), depth-1 B prefetch, zero-init acc, s=(x2-2M^)+c2, 0.0427
// margin, exact fmaf-chain rescore (bit-identical), overflow full scan, fused epilogue.
// New vs R7: cmax2 via in-block reduce of staged c2s; last-block ticket runs the
// finalize (bit-identical double reduction of old vq_finalize) -> one fewer launch.
__global__ __launch_bounds__(256, 4) void vq_main(const float* __restrict__ latents,
                                                  const float* __restrict__ codebook,
                                                  const uint4* __restrict__ cbB,
                                                  const float* __restrict__ c2g,
                                                  float* __restrict__ out_st,
                                                  float* __restrict__ out_codes,
                                                  int* __restrict__ bins,
                                                  double* __restrict__ loss_part,
                                                  int* __restrict__ done_cnt,
                                                  float* __restrict__ out3) {
  #pragma clang fp contract(off)
  __shared__ __align__(16) float xs[64 * XS_STRIDE];  // 17408 B (reused by finalize)
  __shared__ float x2s[64];
  __shared__ float c2s[K_CODES];
  __shared__ float wmaxs[4];
  __shared__ float thr[64];
  __shared__ float pmin[4][64];
  __shared__ int cand_cnt[64];
  __shared__ int cand_k[64][16];
  __shared__ int rowk[64];
  __shared__ float pvv[4][64];
  __shared__ int pkk[4][64];
  __shared__ int ovf_rows[64];
  __shared__ int ovf_cnt;
  __shared__ double wsum[4];
  __shared__ int ticket_s;

  const int t = threadIdx.x;
  const int lane = t & 63;
  const int w = t >> 6;
  const int m = lane & 15;
  const int kq = lane >> 4;
  const int row0 = blockIdx.x * 64;

  // stage latents tile (coalesced) + c2 + zero counters
  {
    const float4* src = (const float4*)(latents + (size_t)row0 * DIMS);
    #pragma unroll
    for (int p = 0; p < 4; ++p) {
      const int f = p * 256 + t;
      *(float4*)&xs[(f >> 4) * XS_STRIDE + (f & 15) * 4] = src[f];
    }
    c2s[t] = c2g[t];
    c2s[t + 256] = c2g[t + 256];
    if (t < 64) cand_cnt[t] = 0;
    if (t == 0) ovf_cnt = 0;
  }
  __syncthreads();

  // exact x2 per row (serial form, as the 78us round) + cmax2 wave-reduce from c2s
  if (t < 64) {
    const float* xr = xs + t * XS_STRIDE;
    float r[8];
    #pragma unroll
    for (int j = 0; j < 8; ++j) r[j] = xr[j] * xr[j];
    #pragma unroll
    for (int i = 8; i < 64; i += 8) {
      #pragma unroll
      for (int j = 0; j < 8; ++j) r[j] += xr[i + j] * xr[i + j];
    }
    x2s[t] = ((r[0] + r[1]) + (r[2] + r[3])) + ((r[4] + r[5]) + (r[6] + r[7]));
  }
  {
    float mm = fmaxf(c2s[t], c2s[t + 256]);
    #pragma unroll
    for (int off = 1; off < 64; off <<= 1) mm = fmaxf(mm, __shfl_xor(mm, off));
    if (lane == 0) wmaxs[w] = mm;
  }
  __syncthreads();

  // A fragments for all 4 M-tiles: lane holds A[row=T*16+m][k=kq*8+j] (+32 for frag1)
  bf16x8 af0[4], af1[4];
  #pragma unroll
  for (int T = 0; T < 4; ++T) {
    const float* xr = xs + (T * 16 + m) * XS_STRIDE + kq * 8;
    const float4 a0 = *(const float4*)&xr[0];
    const float4 a1 = *(const float4*)&xr[4];
    const float4 b0 = *(const float4*)&xr[32];
    const float4 b1 = *(const float4*)&xr[36];
    B8 pa, pb;
    pa.u.x = bpack(a0.x, a0.y); pa.u.y = bpack(a0.z, a0.w);
    pa.u.z = bpack(a1.x, a1.y); pa.u.w = bpack(a1.z, a1.w);
    pb.u.x = bpack(b0.x, b0.y); pb.u.y = bpack(b0.z, b0.w);
    pb.u.z = bpack(b1.x, b1.y); pb.u.w = bpack(b1.z, b1.w);
    af0[T] = pa.h;
    af1[T] = pb.h;
  }

  // C/D mapping (HW-verified): col = lane&15 (code), row-in-tile = kq*4 + reg.
  float x2r[4][4];
  #pragma unroll
  for (int T = 0; T < 4; ++T)
    #pragma unroll
    for (int j = 0; j < 4; ++j) x2r[T][j] = x2s[T * 16 + kq * 4 + j];
  const int ct0 = w * 8;

  // ---- sweep 1: approx min per row over this wave's code quarter (R7-proven) ----
  float mv[4][4];
  #pragma unroll
  for (int T = 0; T < 4; ++T)
    #pragma unroll
    for (int j = 0; j < 4; ++j) mv[T][j] = __builtin_inff();

  B8 cb0, cb1, nb0, nb1;
  cb0.u = cbB[ct0 * 128 + lane * 2 + 0];
  cb1.u = cbB[ct0 * 128 + lane * 2 + 1];
  #pragma unroll 1
  for (int q = 0; q < 8; ++q) {
    const int ct = ct0 + q;
    if (q < 7) {
      nb0.u = cbB[(ct + 1) * 128 + lane * 2 + 0];
      nb1.u = cbB[(ct + 1) * 128 + lane * 2 + 1];
    }
    const float c2v = c2s[ct * 16 + m];
    #pragma unroll
    for (int T = 0; T < 4; ++T) {
      f32x4 acc = {0.f, 0.f, 0.f, 0.f};
      acc = __builtin_amdgcn_mfma_f32_16x16x32_bf16(af0[T], cb0.h, acc, 0, 0, 0);
      acc = __builtin_amdgcn_mfma_f32_16x16x32_bf16(af1[T], cb1.h, acc, 0, 0, 0);
      #pragma unroll
      for (int j = 0; j < 4; ++j) {
        const float s = (x2r[T][j] - 2.0f * acc[j]) + c2v;
        mv[T][j] = fminf(mv[T][j], s);
      }
    }
    cb0 = nb0;
    cb1 = nb1;
  }
  // reduce min across the 16 lanes sharing rows (xor 1,2,4,8 flips m only)
  #pragma unroll
  for (int T = 0; T < 4; ++T)
    #pragma unroll
    for (int j = 0; j < 4; ++j) {
      float v = mv[T][j];
      #pragma unroll
      for (int off = 1; off < 16; off <<= 1) v = fminf(v, __shfl_xor(v, off));
      mv[T][j] = v;
    }
  if (m == 0) {
    #pragma unroll
    for (int T = 0; T < 4; ++T)
      #pragma unroll
      for (int j = 0; j < 4; ++j) pmin[w][T * 16 + kq * 4 + j] = mv[T][j];
  }
  __syncthreads();
  if (t < 64) {
    const float gmin = fminf(fminf(pmin[0][t], pmin[1][t]), fminf(pmin[2][t], pmin[3][t]));
    const float cmax = sqrtf(fmaxf(fmaxf(wmaxs[0], wmaxs[1]), fmaxf(wmaxs[2], wmaxs[3]))) * 1.0001f;
    // two-sided bf16 margin (proven coefficient from passing rounds) + slack
    thr[t] = gmin + (sqrtf(x2s[t]) * cmax * 0.0427f + 1e-3f);
  }
  __syncthreads();

  // ---- sweep 2: deterministic recompute over the same quarter, collect candidates ----
  float thrr[4][4];
  #pragma unroll
  for (int T = 0; T < 4; ++T)
    #pragma unroll
    for (int j = 0; j < 4; ++j) thrr[T][j] = thr[T * 16 + kq * 4 + j];

  cb0.u = cbB[ct0 * 128 + lane * 2 + 0];
  cb1.u = cbB[ct0 * 128 + lane * 2 + 1];
  #pragma unroll 1
  for (int q = 0; q < 8; ++q) {
    const int ct = ct0 + q;
    if (q < 7) {
      nb0.u = cbB[(ct + 1) * 128 + lane * 2 + 0];
      nb1.u = cbB[(ct + 1) * 128 + lane * 2 + 1];
    }
    const float c2v = c2s[ct * 16 + m];
    const int k = ct * 16 + m;
    #pragma unroll
    for (int T = 0; T < 4; ++T) {
      f32x4 acc = {0.f, 0.f, 0.f, 0.f};
      acc = __builtin_amdgcn_mfma_f32_16x16x32_bf16(af0[T], cb0.h, acc, 0, 0, 0);
      acc = __builtin_amdgcn_mfma_f32_16x16x32_bf16(af1[T], cb1.h, acc, 0, 0, 0);
      #pragma unroll
      for (int j = 0; j < 4; ++j) {
        const float s = (x2r[T][j] - 2.0f * acc[j]) + c2v;
        if (s <= thrr[T][j]) {
          const int rr = T * 16 + kq * 4 + j;
          const int pos = atomicAdd(&cand_cnt[rr], 1);
          if (pos < 16) cand_k[rr][pos] = k;
        }
      }
    }
    cb0 = nb0;
    cb1 = nb1;
  }
  __syncthreads();

  // ---- exact rescore: 4 threads per row (phase = t>>6), candidates strided ----
  {
    const int rr = t & 63;
    const int ph = t >> 6;
    const int cnt = cand_cnt[rr];
    float bv = __builtin_inff();
    int bk = 0x7fffffff;
    if (cnt <= 16) {
      const float* xr = xs + rr * XS_STRIDE;
      const float x2e = x2s[rr];
      for (int c = ph; c < cnt; c += 4) {
        const int k = cand_k[rr][c];
        const float M = exact_dot(xr, codebook + k * DIMS);
        const float s = (x2e - 2.0f * M) + c2s[k];
        if (s < bv || (s == bv && k < bk)) { bv = s; bk = k; }
      }
    } else if (ph == 0) {
      const int p = atomicAdd(&ovf_cnt, 1);
      ovf_rows[p] = rr;
    }
    pvv[ph][rr] = bv;
    pkk[ph][rr] = bk;
  }
  __syncthreads();
  if (t < 64) {
    float bv = pvv[0][t];
    int bk = pkk[0][t];
    #pragma unroll
    for (int ph = 1; ph < 4; ++ph) {
      const float v = pvv[ph][t];
      const int k = pkk[ph][t];
      if (v < bv || (v == bv && k < bk)) { bv = v; bk = k; }
    }
    rowk[t] = bk;
  }
  __syncthreads();

  // overflow rows (rare): exact wave-parallel full scan by wave 0
  if (w == 0) {
    const int no = ovf_cnt;
    for (int o = 0; o < no; ++o) {
      const int rr = ovf_rows[o];
      const float* xr = xs + rr * XS_STRIDE;
      const float x2e = x2s[rr];
      float bv = __builtin_inff();
      int bk = 0x7fffffff;
      for (int k = lane; k < K_CODES; k += 64) {
        const float M = exact_dot(xr, codebook + k * DIMS);
        const float s = (x2e - 2.0f * M) + c2s[k];
        if (s < bv || (s == bv && k < bk)) { bv = s; bk = k; }
      }
      #pragma unroll
      for (int off = 1; off < 64; off <<= 1) {
        const float ov = __shfl_xor(bv, off);
        const int oi = __shfl_xor(bk, off);
        if (ov < bv || (ov == bv && oi < bk)) { bv = ov; bk = oi; }
      }
      if (lane == 0) rowk[rr] = bk;
    }
  }
  __syncthreads();

  // ---- outputs: codes + bins + fused STE/loss epilogue ----
  if (t < 64) {
    const int k = rowk[t];
    out_codes[row0 + t] = (float)k;
    atomicAdd(&bins[k], 1);
  }
  double dacc = 0.0;
  {
    float4* dst = (float4*)out_st + (size_t)row0 * 16;
    #pragma unroll
    for (int p = 0; p < 4; ++p) {
      const int f = p * 256 + t;
      const int r = f >> 4;
      const int d4 = f & 15;
      const int k = rowk[r];
      const float4 q = *(const float4*)&codebook[k * DIMS + d4 * 4];
      const float4 l = *(const float4*)&xs[r * XS_STRIDE + d4 * 4];
      float4 o;
      o.x = l.x + (q.x - l.x);  // straight-through, np rounding order
      o.y = l.y + (q.y - l.y);
      o.z = l.z + (q.z - l.z);
      o.w = l.w + (q.w - l.w);
      dst[f] = o;
      const float dx = l.x - q.x, dy = l.y - q.y, dz = l.z - q.z, dw = l.w - q.w;
      dacc += (double)dx * (double)dx;
      dacc += (double)dy * (double)dy;
      dacc += (double)dz * (double)dz;
      dacc += (double)dw * (double)dw;
    }
  }
  #pragma unroll
  for (int off = 32; off > 0; off >>= 1) dacc += __shfl_down(dacc, off);
  if (lane == 0) wsum[w] = dacc;
  __syncthreads();

  // ---- fused finalize: last-block ticket (device-scope, XCD-safe) ----
  if (t == 0) {
    loss_part[blockIdx.x] = (wsum[0] + wsum[1]) + (wsum[2] + wsum[3]);
    __threadfence();                       // release: loss_part + our bins atomics
    ticket_s = atomicAdd(done_cnt, 1);
  }
  __syncthreads();
  if (ticket_s == NBLK - 1) {
    __threadfence();                       // acquire side
    double* red2 = (double*)xs;            // reuse xs (4352 floats; need 512 doubles)
    double* redl2 = (double*)&xs[512];
    const int b0 = __hip_atomic_load(&bins[t], __ATOMIC_RELAXED, __HIP_MEMORY_SCOPE_AGENT);
    const int b1 = __hip_atomic_load(&bins[t + 256], __ATOMIC_RELAXED, __HIP_MEMORY_SCOPE_AGENT);
    const double p0 = (double)b0 / 131072.0;
    const double p1 = (double)b1 / 131072.0;
    // matches old vq_finalize's level-0 pair (t, t+256) exactly
    red2[t] = (-p0 * log(p0 + 1e-10)) + (-p1 * log(p1 + 1e-10));
    double lp[8];
    #pragma unroll
    for (int i = 0; i < 8; ++i)
      lp[i] = __hip_atomic_load(&loss_part[t + 256 * i], __ATOMIC_RELAXED, __HIP_MEMORY_SCOPE_AGENT);
    // matches old finalize association: ((t + t+512) + (t+1024 + t+1536)) + ((t+256 + t+768) + (t+1280 + t+1792))
    redl2[t] = ((lp[0] + lp[2]) + (lp[4] + lp[6])) + ((lp[1] + lp[3]) + (lp[5] + lp[7]));
    __syncthreads();
    for (int s = 128; s > 0; s >>= 1) {
      if (t < s) { red2[t] += red2[t + s]; redl2[t] += redl2[t + s]; }
      __syncthreads();
    }
    if (t == 0) {
      const double mean = redl2[0] / 8388608.0;
      out3[0] = (float)(0.25 * mean);  // commitment * COMMITMENT_COST
      out3[1] = (float)mean;           // codebook_loss (same squares bitwise)
      out3[2] = (float)exp(red2[0]);   // perplexity
    }
  }
}

extern "C" void kernel_launch(void* const* d_in, const int* in_sizes, int n_in,
                              void* d_out, int out_size, void* d_ws, size_t ws_size,
                              hipStream_t stream) {
  const float* latents = (const float*)d_in[0];
  const float* codebook = (const float*)d_in[1];

  float* out = (float*)d_out;
  float* out_st = out;                              // 8388608
  float* out_codes = out + (size_t)N_ROWS * DIMS;   // 131072 (codes as float)
  float* out3 = out_codes + N_ROWS;                 // 3 scalars

  char* ws = (char*)d_ws;
  double* loss_part = (double*)ws;                  // [0, 16384)       2048 doubles
  int* bins = (int*)(ws + 16384);                   // [16384, 18432)
  float* c2g = (float*)(ws + 18432);                // [18432, 20480)
  int* done_cnt = (int*)(ws + 20480);               // [20480, 20484)
  uint4* cbB = (uint4*)(ws + 21504);                // [21504, 87040)   64 KB bf16 frags

  hipLaunchKernelGGL(vq_init, dim3(64), dim3(256), 0, stream,
                     codebook, bins, c2g, cbB, done_cnt);
  hipLaunchKernelGGL(vq_main, dim3(NBLK), dim3(256), 0, stream,
                     latents, codebook, cbB, c2g, out_st, out_codes, bins, loss_part,
                     done_cnt, out3);
}

// Round 10
// 148.038 us; speedup vs baseline: 1.3119x; 1.3119x over previous
//
#include <hip/hip_runtime.h>
#include <math.h>

#define N_ROWS 131072
#define DIMS 64
#define K_CODES 512
#define XS_STRIDE 68
#define NBLK 2048

typedef __attribute__((ext_vector_type(8))) short bf16x8;
typedef __attribute__((ext_vector_type(4))) float f32x4;

union B8 { uint4 u; bf16x8 h; };

// RNE float->bf16 pack (two floats -> one uint, low=first)
__device__ inline unsigned bpack(float a, float b) {
  unsigned ua = __float_as_uint(a), ub = __float_as_uint(b);
  ua = (ua + 0x7FFFu + ((ua >> 16) & 1u)) >> 16;
  ub = (ub + 0x7FFFu + ((ub >> 16) & 1u)) >> 16;
  return ua | (ub << 16);
}

// exact reference dot: single fmaf chain over ascending d (bitwise as prior rounds)
__device__ inline float exact_dot(const float* __restrict__ xr, const float* __restrict__ cr) {
  float m = 0.f;
  #pragma unroll
  for (int d4 = 0; d4 < 16; ++d4) {
    const float4 c = *(const float4*)&cr[d4 * 4];
    const float4 x = *(const float4*)&xr[d4 * 4];
    m = fmaf(x.x, c.x, m);
    m = fmaf(x.y, c.y, m);
    m = fmaf(x.z, c.z, m);
    m = fmaf(x.w, c.w, m);
  }
  return m;
}

// ---------------- K0 (64 blocks, fully parallel): bins zero + exact c2 + bf16 frags
// cbB layout (as passing rounds): entry e = ct*128 + lane*2 + half;
//   code = ct*16 + (lane&15), dims [(lane>>4)*8 + half*32 .. +8). Plain bf16(c).
__global__ __launch_bounds__(256) void vq_init(const float* __restrict__ codebook,
                                               int* __restrict__ bins,
                                               float* __restrict__ c2g,
                                               uint4* __restrict__ cbB) {
  #pragma clang fp contract(off)
  const int t = threadIdx.x;
  const int b = blockIdx.x;
  if (t < 64) {
    const int e = b * 64 + t;          // 64 blocks x 64 = 4096 entries
    const int ct = e >> 7;
    const int q = e & 127;
    const int lane_id = q >> 1;
    const int half = q & 1;
    const int code = ct * 16 + (lane_id & 15);
    const int dbase = ((lane_id >> 4) * 8) + half * 32;
    const float* src = codebook + code * DIMS + dbase;
    const float4 a = *(const float4*)&src[0];
    const float4 c = *(const float4*)&src[4];
    uint4 u;
    u.x = bpack(a.x, a.y);
    u.y = bpack(a.z, a.w);
    u.z = bpack(c.x, c.y);
    u.w = bpack(c.z, c.w);
    cbB[e] = u;
  } else if (t < 72) {
    // exact c2: numpy pairwise_sum, n=64 (bitwise as prior passing rounds)
    const int k = b * 8 + (t - 64);
    const float* cr = codebook + k * DIMS;
    float r[8];
    #pragma unroll
    for (int j = 0; j < 8; ++j) r[j] = cr[j] * cr[j];
    for (int i = 8; i < 64; i += 8) {
      #pragma unroll
      for (int j = 0; j < 8; ++j) r[j] += cr[i + j] * cr[i + j];  // contract OFF
    }
    c2g[k] = ((r[0] + r[1]) + (r[2] + r[3])) + ((r[4] + r[5]) + (r[6] + r[7]));
  } else if (t < 80) {
    bins[b * 8 + (t - 72)] = 0;
  }
}

// ---------------- K1: MFMA approx scores -> candidates -> exact rescore -> outputs
// Round-7 proven core (78 us measured): wave w covers all 64 rows (4 M-tiles) x its
// code quarter (8 tiles), depth-1 B prefetch, zero-init acc, s=(x2-2M^)+c2, 0.0427
// margin, exact fmaf-chain rescore (bit-identical), overflow full scan, fused epilogue.
// cmax2 via in-block wave-reduce of staged c2s. NO device-scope fences (R9 lesson:
// __threadfence -> per-block L2 writeback on multi-XCD -> 2x uniform slowdown).
__global__ __launch_bounds__(256, 4) void vq_main(const float* __restrict__ latents,
                                                  const float* __restrict__ codebook,
                                                  const uint4* __restrict__ cbB,
                                                  const float* __restrict__ c2g,
                                                  float* __restrict__ out_st,
                                                  float* __restrict__ out_codes,
                                                  int* __restrict__ bins,
                                                  double* __restrict__ loss_part) {
  #pragma clang fp contract(off)
  __shared__ __align__(16) float xs[64 * XS_STRIDE];  // 17408 B
  __shared__ float x2s[64];
  __shared__ float c2s[K_CODES];
  __shared__ float wmaxs[4];
  __shared__ float thr[64];
  __shared__ float pmin[4][64];
  __shared__ int cand_cnt[64];
  __shared__ int cand_k[64][16];
  __shared__ int rowk[64];
  __shared__ float pvv[4][64];
  __shared__ int pkk[4][64];
  __shared__ int ovf_rows[64];
  __shared__ int ovf_cnt;
  __shared__ double wsum[4];

  const int t = threadIdx.x;
  const int lane = t & 63;
  const int w = t >> 6;
  const int m = lane & 15;
  const int kq = lane >> 4;
  const int row0 = blockIdx.x * 64;

  // stage latents tile (coalesced) + c2 + zero counters
  {
    const float4* src = (const float4*)(latents + (size_t)row0 * DIMS);
    #pragma unroll
    for (int p = 0; p < 4; ++p) {
      const int f = p * 256 + t;
      *(float4*)&xs[(f >> 4) * XS_STRIDE + (f & 15) * 4] = src[f];
    }
    c2s[t] = c2g[t];
    c2s[t + 256] = c2g[t + 256];
    if (t < 64) cand_cnt[t] = 0;
    if (t == 0) ovf_cnt = 0;
  }
  __syncthreads();

  // exact x2 per row (serial form, as the 78us round) + cmax2 wave-reduce from c2s
  if (t < 64) {
    const float* xr = xs + t * XS_STRIDE;
    float r[8];
    #pragma unroll
    for (int j = 0; j < 8; ++j) r[j] = xr[j] * xr[j];
    #pragma unroll
    for (int i = 8; i < 64; i += 8) {
      #pragma unroll
      for (int j = 0; j < 8; ++j) r[j] += xr[i + j] * xr[i + j];
    }
    x2s[t] = ((r[0] + r[1]) + (r[2] + r[3])) + ((r[4] + r[5]) + (r[6] + r[7]));
  }
  {
    float mm = fmaxf(c2s[t], c2s[t + 256]);
    #pragma unroll
    for (int off = 1; off < 64; off <<= 1) mm = fmaxf(mm, __shfl_xor(mm, off));
    if (lane == 0) wmaxs[w] = mm;
  }
  __syncthreads();

  // A fragments for all 4 M-tiles: lane holds A[row=T*16+m][k=kq*8+j] (+32 for frag1)
  bf16x8 af0[4], af1[4];
  #pragma unroll
  for (int T = 0; T < 4; ++T) {
    const float* xr = xs + (T * 16 + m) * XS_STRIDE + kq * 8;
    const float4 a0 = *(const float4*)&xr[0];
    const float4 a1 = *(const float4*)&xr[4];
    const float4 b0 = *(const float4*)&xr[32];
    const float4 b1 = *(const float4*)&xr[36];
    B8 pa, pb;
    pa.u.x = bpack(a0.x, a0.y); pa.u.y = bpack(a0.z, a0.w);
    pa.u.z = bpack(a1.x, a1.y); pa.u.w = bpack(a1.z, a1.w);
    pb.u.x = bpack(b0.x, b0.y); pb.u.y = bpack(b0.z, b0.w);
    pb.u.z = bpack(b1.x, b1.y); pb.u.w = bpack(b1.z, b1.w);
    af0[T] = pa.h;
    af1[T] = pb.h;
  }

  // C/D mapping (HW-verified): col = lane&15 (code), row-in-tile = kq*4 + reg.
  float x2r[4][4];
  #pragma unroll
  for (int T = 0; T < 4; ++T)
    #pragma unroll
    for (int j = 0; j < 4; ++j) x2r[T][j] = x2s[T * 16 + kq * 4 + j];
  const int ct0 = w * 8;

  // ---- sweep 1: approx min per row over this wave's code quarter (R7-proven) ----
  float mv[4][4];
  #pragma unroll
  for (int T = 0; T < 4; ++T)
    #pragma unroll
    for (int j = 0; j < 4; ++j) mv[T][j] = __builtin_inff();

  B8 cb0, cb1, nb0, nb1;
  cb0.u = cbB[ct0 * 128 + lane * 2 + 0];
  cb1.u = cbB[ct0 * 128 + lane * 2 + 1];
  #pragma unroll 1
  for (int q = 0; q < 8; ++q) {
    const int ct = ct0 + q;
    if (q < 7) {
      nb0.u = cbB[(ct + 1) * 128 + lane * 2 + 0];
      nb1.u = cbB[(ct + 1) * 128 + lane * 2 + 1];
    }
    const float c2v = c2s[ct * 16 + m];
    #pragma unroll
    for (int T = 0; T < 4; ++T) {
      f32x4 acc = {0.f, 0.f, 0.f, 0.f};
      acc = __builtin_amdgcn_mfma_f32_16x16x32_bf16(af0[T], cb0.h, acc, 0, 0, 0);
      acc = __builtin_amdgcn_mfma_f32_16x16x32_bf16(af1[T], cb1.h, acc, 0, 0, 0);
      #pragma unroll
      for (int j = 0; j < 4; ++j) {
        const float s = (x2r[T][j] - 2.0f * acc[j]) + c2v;
        mv[T][j] = fminf(mv[T][j], s);
      }
    }
    cb0 = nb0;
    cb1 = nb1;
  }
  // reduce min across the 16 lanes sharing rows (xor 1,2,4,8 flips m only)
  #pragma unroll
  for (int T = 0; T < 4; ++T)
    #pragma unroll
    for (int j = 0; j < 4; ++j) {
      float v = mv[T][j];
      #pragma unroll
      for (int off = 1; off < 16; off <<= 1) v = fminf(v, __shfl_xor(v, off));
      mv[T][j] = v;
    }
  if (m == 0) {
    #pragma unroll
    for (int T = 0; T < 4; ++T)
      #pragma unroll
      for (int j = 0; j < 4; ++j) pmin[w][T * 16 + kq * 4 + j] = mv[T][j];
  }
  __syncthreads();
  if (t < 64) {
    const float gmin = fminf(fminf(pmin[0][t], pmin[1][t]), fminf(pmin[2][t], pmin[3][t]));
    const float cmax = sqrtf(fmaxf(fmaxf(wmaxs[0], wmaxs[1]), fmaxf(wmaxs[2], wmaxs[3]))) * 1.0001f;
    // two-sided bf16 margin (proven coefficient from passing rounds) + slack
    thr[t] = gmin + (sqrtf(x2s[t]) * cmax * 0.0427f + 1e-3f);
  }
  __syncthreads();

  // ---- sweep 2: deterministic recompute over the same quarter, collect candidates ----
  float thrr[4][4];
  #pragma unroll
  for (int T = 0; T < 4; ++T)
    #pragma unroll
    for (int j = 0; j < 4; ++j) thrr[T][j] = thr[T * 16 + kq * 4 + j];

  cb0.u = cbB[ct0 * 128 + lane * 2 + 0];
  cb1.u = cbB[ct0 * 128 + lane * 2 + 1];
  #pragma unroll 1
  for (int q = 0; q < 8; ++q) {
    const int ct = ct0 + q;
    if (q < 7) {
      nb0.u = cbB[(ct + 1) * 128 + lane * 2 + 0];
      nb1.u = cbB[(ct + 1) * 128 + lane * 2 + 1];
    }
    const float c2v = c2s[ct * 16 + m];
    const int k = ct * 16 + m;
    #pragma unroll
    for (int T = 0; T < 4; ++T) {
      f32x4 acc = {0.f, 0.f, 0.f, 0.f};
      acc = __builtin_amdgcn_mfma_f32_16x16x32_bf16(af0[T], cb0.h, acc, 0, 0, 0);
      acc = __builtin_amdgcn_mfma_f32_16x16x32_bf16(af1[T], cb1.h, acc, 0, 0, 0);
      #pragma unroll
      for (int j = 0; j < 4; ++j) {
        const float s = (x2r[T][j] - 2.0f * acc[j]) + c2v;
        if (s <= thrr[T][j]) {
          const int rr = T * 16 + kq * 4 + j;
          const int pos = atomicAdd(&cand_cnt[rr], 1);
          if (pos < 16) cand_k[rr][pos] = k;
        }
      }
    }
    cb0 = nb0;
    cb1 = nb1;
  }
  __syncthreads();

  // ---- exact rescore: 4 threads per row (phase = t>>6), candidates strided ----
  {
    const int rr = t & 63;
    const int ph = t >> 6;
    const int cnt = cand_cnt[rr];
    float bv = __builtin_inff();
    int bk = 0x7fffffff;
    if (cnt <= 16) {
      const float* xr = xs + rr * XS_STRIDE;
      const float x2e = x2s[rr];
      for (int c = ph; c < cnt; c += 4) {
        const int k = cand_k[rr][c];
        const float M = exact_dot(xr, codebook + k * DIMS);
        const float s = (x2e - 2.0f * M) + c2s[k];
        if (s < bv || (s == bv && k < bk)) { bv = s; bk = k; }
      }
    } else if (ph == 0) {
      const int p = atomicAdd(&ovf_cnt, 1);
      ovf_rows[p] = rr;
    }
    pvv[ph][rr] = bv;
    pkk[ph][rr] = bk;
  }
  __syncthreads();
  if (t < 64) {
    float bv = pvv[0][t];
    int bk = pkk[0][t];
    #pragma unroll
    for (int ph = 1; ph < 4; ++ph) {
      const float v = pvv[ph][t];
      const int k = pkk[ph][t];
      if (v < bv || (v == bv && k < bk)) { bv = v; bk = k; }
    }
    rowk[t] = bk;
  }
  __syncthreads();

  // overflow rows (rare): exact wave-parallel full scan by wave 0
  if (w == 0) {
    const int no = ovf_cnt;
    for (int o = 0; o < no; ++o) {
      const int rr = ovf_rows[o];
      const float* xr = xs + rr * XS_STRIDE;
      const float x2e = x2s[rr];
      float bv = __builtin_inff();
      int bk = 0x7fffffff;
      for (int k = lane; k < K_CODES; k += 64) {
        const float M = exact_dot(xr, codebook + k * DIMS);
        const float s = (x2e - 2.0f * M) + c2s[k];
        if (s < bv || (s == bv && k < bk)) { bv = s; bk = k; }
      }
      #pragma unroll
      for (int off = 1; off < 64; off <<= 1) {
        const float ov = __shfl_xor(bv, off);
        const int oi = __shfl_xor(bk, off);
        if (ov < bv || (ov == bv && oi < bk)) { bv = ov; bk = oi; }
      }
      if (lane == 0) rowk[rr] = bk;
    }
  }
  __syncthreads();

  // ---- outputs: codes + bins + fused STE/loss epilogue ----
  if (t < 64) {
    const int k = rowk[t];
    out_codes[row0 + t] = (float)k;
    atomicAdd(&bins[k], 1);
  }
  double dacc = 0.0;
  {
    float4* dst = (float4*)out_st + (size_t)row0 * 16;
    #pragma unroll
    for (int p = 0; p < 4; ++p) {
      const int f = p * 256 + t;
      const int r = f >> 4;
      const int d4 = f & 15;
      const int k = rowk[r];
      const float4 q = *(const float4*)&codebook[k * DIMS + d4 * 4];
      const float4 l = *(const float4*)&xs[r * XS_STRIDE + d4 * 4];
      float4 o;
      o.x = l.x + (q.x - l.x);  // straight-through, np rounding order
      o.y = l.y + (q.y - l.y);
      o.z = l.z + (q.z - l.z);
      o.w = l.w + (q.w - l.w);
      dst[f] = o;
      const float dx = l.x - q.x, dy = l.y - q.y, dz = l.z - q.z, dw = l.w - q.w;
      dacc += (double)dx * (double)dx;
      dacc += (double)dy * (double)dy;
      dacc += (double)dz * (double)dz;
      dacc += (double)dw * (double)dw;
    }
  }
  #pragma unroll
  for (int off = 32; off > 0; off >>= 1) dacc += __shfl_down(dacc, off);
  if (lane == 0) wsum[w] = dacc;
  __syncthreads();
  if (t == 0) loss_part[blockIdx.x] = (wsum[0] + wsum[1]) + (wsum[2] + wsum[3]);
}

// ---------------- K3: reduce loss partials + perplexity + scalar outputs ----------
__global__ __launch_bounds__(512) void vq_finalize(const int* __restrict__ bins,
                                                   const double* __restrict__ loss_part,
                                                   float* __restrict__ out3) {
  __shared__ double red[512];
  __shared__ double redl[512];
  const int t = threadIdx.x;
  const double p = (double)bins[t] / 131072.0;
  red[t] = -p * log(p + 1e-10);
  redl[t] = (loss_part[t] + loss_part[t + 512]) + (loss_part[t + 1024] + loss_part[t + 1536]);
  __syncthreads();
  for (int s = 256; s > 0; s >>= 1) {
    if (t < s) { red[t] += red[t + s]; redl[t] += redl[t + s]; }
    __syncthreads();
  }
  if (t == 0) {
    const double mean = redl[0] / 8388608.0;
    out3[0] = (float)(0.25 * mean);  // commitment * COMMITMENT_COST
    out3[1] = (float)mean;           // codebook_loss (same squares bitwise)
    out3[2] = (float)exp(red[0]);    // perplexity
  }
}

extern "C" void kernel_launch(void* const* d_in, const int* in_sizes, int n_in,
                              void* d_out, int out_size, void* d_ws, size_t ws_size,
                              hipStream_t stream) {
  const float* latents = (const float*)d_in[0];
  const float* codebook = (const float*)d_in[1];

  float* out = (float*)d_out;
  float* out_st = out;                              // 8388608
  float* out_codes = out + (size_t)N_ROWS * DIMS;   // 131072 (codes as float)
  float* out3 = out_codes + N_ROWS;                 // 3 scalars

  char* ws = (char*)d_ws;
  double* loss_part = (double*)ws;                  // [0, 16384)       2048 doubles
  int* bins = (int*)(ws + 16384);                   // [16384, 18432)
  float* c2g = (float*)(ws + 18432);                // [18432, 20480)
  uint4* cbB = (uint4*)(ws + 21504);                // [21504, 87040)   64 KB bf16 frags

  hipLaunchKernelGGL(vq_init, dim3(64), dim3(256), 0, stream,
                     codebook, bins, c2g, cbB);
  hipLaunchKernelGGL(vq_main, dim3(NBLK), dim3(256), 0, stream,
                     latents, codebook, cbB, c2g, out_st, out_codes, bins, loss_part);
  hipLaunchKernelGGL(vq_finalize, dim3(1), dim3(512), 0, stream,
                     bins, loss_part, out3);
}